// Round 2
// baseline (2585.190 us; speedup 1.0000x reference)
//
#include <hip/hip_runtime.h>

#define H 1024
#define SEQ 2048
#define BATCH 8
#define MROWS (BATCH * SEQ)   // 16384
#define KD H                  // GEMM K dim = 1024

typedef _Float16 f16;
typedef _Float16 f16x8 __attribute__((ext_vector_type(8)));
typedef _Float16 f16x4 __attribute__((ext_vector_type(4)));
typedef float f32x4 __attribute__((ext_vector_type(4)));

__device__ __forceinline__ float gate_fn(float x) {
    float s = 1.0f / (1.0f + __expf(-x));
    return fminf(fmaxf(1.2f * s - 0.1f, 0.0f), 1.0f);
}

__device__ __forceinline__ void gload_lds16(const void* g, void* lds) {
    __builtin_amdgcn_global_load_lds(
        (const __attribute__((address_space(1))) unsigned int*)g,
        (__attribute__((address_space(3))) unsigned int*)lds, 16, 0, 0);
}

// ---------------- fp32 -> fp16 convert (8 elems/thread) ----------------
__global__ void k_f32_to_f16(const float* __restrict__ in, f16* __restrict__ out) {
    size_t i = ((size_t)blockIdx.x * blockDim.x + threadIdx.x) * 8;
    float4 v0 = *(const float4*)(in + i);
    float4 v1 = *(const float4*)(in + i + 4);
    f16x8 o;
    o[0] = (f16)v0.x; o[1] = (f16)v0.y; o[2] = (f16)v0.z; o[3] = (f16)v0.w;
    o[4] = (f16)v1.x; o[5] = (f16)v1.y; o[6] = (f16)v1.z; o[7] = (f16)v1.w;
    *(f16x8*)(out + i) = o;
}

// ---------------- transpose + convert: WT[n][k] = (f16)W[k][n] ----------------
__global__ void k_transpose_f16(const float* __restrict__ Wsrc, f16* __restrict__ WT,
                                int K, int N) {
    __shared__ float tile[32][33];
    int n0 = blockIdx.x * 32, k0 = blockIdx.y * 32;
    for (int i = threadIdx.y; i < 32; i += 8)
        tile[i][threadIdx.x] = Wsrc[(size_t)(k0 + i) * N + n0 + threadIdx.x];
    __syncthreads();
    for (int i = threadIdx.y; i < 32; i += 8)
        WT[(size_t)(n0 + i) * K + k0 + threadIdx.x] = (f16)tile[threadIdx.x][i];
}

// ---------------- proj GEMM: P16 = (f16)(A @ BT^T), A[M][K], BT[N][K] ----------------
__global__ __launch_bounds__(256) void k_proj_gemm(const f16* __restrict__ A,
                                                   const f16* __restrict__ BT,
                                                   f16* __restrict__ P16) {
    __shared__ alignas(16) f16 Alds[128 * 32];
    __shared__ alignas(16) f16 Blds[128 * 32];
    const int tid = threadIdx.x;
    const int lane = tid & 63, wid = tid >> 6;
    const int l15 = lane & 15, l4 = lane >> 4;
    const int bm = blockIdx.x, bn = blockIdx.y;

    const f16* gA[2]; const f16* gB[2];
    char* ldsA[2]; char* ldsB[2];
#pragma unroll
    for (int it = 0; it < 2; ++it) {
        int c = it * 4 + wid;
        int slot = c * 64 + lane;
        int row = slot >> 2;
        int k16 = (slot & 3) ^ (row & 3);          // pre-swizzled global source
        gA[it] = A + (size_t)(bm * 128 + row) * KD + k16 * 8;
        gB[it] = BT + (size_t)(bn * 128 + row) * KD + k16 * 8;
        ldsA[it] = (char*)Alds + c * 1024;          // wave-uniform LDS base
        ldsB[it] = (char*)Blds + c * 1024;
    }

    int offA[2], offB[8];
#pragma unroll
    for (int m = 0; m < 2; ++m) {
        int row = wid * 32 + m * 16 + l15;
        offA[m] = row * 64 + ((l4 ^ (row & 3)) << 4);  // swizzled ds_read addr
    }
#pragma unroll
    for (int n = 0; n < 8; ++n) {
        int row = n * 16 + l15;
        offB[n] = row * 64 + ((l4 ^ (row & 3)) << 4);
    }

    f32x4 acc[2][8] = {};

    for (int kt = 0; kt < KD / 32; ++kt) {
        __syncthreads();
#pragma unroll
        for (int it = 0; it < 2; ++it) {
            gload_lds16(gA[it], ldsA[it]);
            gload_lds16(gB[it], ldsB[it]);
            gA[it] += 32; gB[it] += 32;
        }
        __syncthreads();
        f16x8 a[2], b[8];
#pragma unroll
        for (int m = 0; m < 2; ++m) a[m] = *(const f16x8*)((const char*)Alds + offA[m]);
#pragma unroll
        for (int n = 0; n < 8; ++n) b[n] = *(const f16x8*)((const char*)Blds + offB[n]);
#pragma unroll
        for (int n = 0; n < 8; ++n)
#pragma unroll
            for (int m = 0; m < 2; ++m)
                acc[m][n] = __builtin_amdgcn_mfma_f32_16x16x32_f16(a[m], b[n], acc[m][n], 0, 0, 0);
    }

#pragma unroll
    for (int m = 0; m < 2; ++m)
#pragma unroll
        for (int n = 0; n < 8; ++n) {
            int col = bn * 128 + n * 16 + l15;
#pragma unroll
            for (int r = 0; r < 4; ++r) {
                int row = bm * 128 + wid * 32 + m * 16 + l4 * 4 + r;
                P16[(size_t)row * H + col] = (f16)acc[m][n][r];
            }
        }
}

// ---------------- step 0 (state==0): elementwise ----------------
__global__ void k_step0(const f16* __restrict__ P16, const float* __restrict__ by,
                        float* __restrict__ Out, f16* __restrict__ S16) {
    size_t idx = ((size_t)blockIdx.x * blockDim.x + threadIdx.x) * 4;
    int row = (int)(idx >> 10);
    int d = (int)(idx & 1023);
    int s = row & (SEQ - 1);
    float inp[4] = {0.f, 0.f, 0.f, 0.f};
    if (s >= 15) {
        f16x4 p = *(const f16x4*)(P16 + (size_t)(row - 15) * H + d);
        inp[0] = (float)p[0]; inp[1] = (float)p[1]; inp[2] = (float)p[2]; inp[3] = (float)p[3];
    }
    float4 outv;
    f16x4 sv;
#pragma unroll
    for (int j = 0; j < 4; ++j) {
        float g = gate_fn(by[H + d + j]);
        float v = fmaxf(g * (inp[j] + by[d + j]), 0.f);
        ((float*)&outv)[j] = v;
        sv[j] = (f16)v;
    }
    *(float4*)(Out + idx) = outv;
    *(f16x4*)(S16 + idx) = sv;
}

// ---------------- step GEMM + fused gate/relu epilogue ----------------
// A = state_f16 [M][K]; BT = WyT [2H][K]; block computes ns tile rows bm*128..+128,
// cols {cand: t*64..+64, gate: 1024+t*64..+64} -> writes new state [128 x 64].
__global__ __launch_bounds__(256) void k_step_gemm(const f16* __restrict__ A,
                                                   const f16* __restrict__ BT,
                                                   const f16* __restrict__ P16,
                                                   const float* __restrict__ by,
                                                   float* __restrict__ Out,
                                                   f16* __restrict__ Snext,
                                                   int stepi) {
    __shared__ alignas(16) f16 Alds[128 * 32];
    __shared__ alignas(16) f16 Blds[128 * 32];
    const int tid = threadIdx.x;
    const int lane = tid & 63, wid = tid >> 6;
    const int l15 = lane & 15, l4 = lane >> 4;
    const int bm = blockIdx.x, t = blockIdx.y;

    const f16* gA[2]; const f16* gB[2];
    char* ldsA[2]; char* ldsB[2];
#pragma unroll
    for (int it = 0; it < 2; ++it) {
        int c = it * 4 + wid;
        int slot = c * 64 + lane;
        int row = slot >> 2;
        int k16 = (slot & 3) ^ (row & 3);
        gA[it] = A + (size_t)(bm * 128 + row) * KD + k16 * 8;
        int rowB = t * 64 + row + (row >= 64 ? 960 : 0);  // cand rows then gate rows
        gB[it] = BT + (size_t)rowB * KD + k16 * 8;
        ldsA[it] = (char*)Alds + c * 1024;
        ldsB[it] = (char*)Blds + c * 1024;
    }

    int offA[2], offB[8];
#pragma unroll
    for (int m = 0; m < 2; ++m) {
        int row = wid * 32 + m * 16 + l15;
        offA[m] = row * 64 + ((l4 ^ (row & 3)) << 4);
    }
#pragma unroll
    for (int n = 0; n < 8; ++n) {
        int row = n * 16 + l15;
        offB[n] = row * 64 + ((l4 ^ (row & 3)) << 4);
    }

    f32x4 acc[2][8] = {};

    for (int kt = 0; kt < KD / 32; ++kt) {
        __syncthreads();
#pragma unroll
        for (int it = 0; it < 2; ++it) {
            gload_lds16(gA[it], ldsA[it]);
            gload_lds16(gB[it], ldsB[it]);
            gA[it] += 32; gB[it] += 32;
        }
        __syncthreads();
        f16x8 a[2], b[8];
#pragma unroll
        for (int m = 0; m < 2; ++m) a[m] = *(const f16x8*)((const char*)Alds + offA[m]);
#pragma unroll
        for (int n = 0; n < 8; ++n) b[n] = *(const f16x8*)((const char*)Blds + offB[n]);
#pragma unroll
        for (int n = 0; n < 8; ++n)
#pragma unroll
            for (int m = 0; m < 2; ++m)
                acc[m][n] = __builtin_amdgcn_mfma_f32_16x16x32_f16(a[m], b[n], acc[m][n], 0, 0, 0);
    }

    // epilogue: acc[m][n] = cand col (d = t*64 + n*16 + l15), acc[m][n+4] = its gate
#pragma unroll
    for (int n = 0; n < 4; ++n) {
        int d = t * 64 + n * 16 + l15;
        float byc = by[d];
        float byg = by[H + d];
#pragma unroll
        for (int m = 0; m < 2; ++m) {
#pragma unroll
            for (int r = 0; r < 4; ++r) {
                int row = bm * 128 + wid * 32 + m * 16 + l4 * 4 + r;
                int s = row & (SEQ - 1);
                float cand = acc[m][n][r] + byc;
                float gl = acc[m][n + 4][r] + byg;
                float g = gate_fn(gl);
                float inp = 0.f;
                if (s >= 15 - stepi)
                    inp = (float)P16[(size_t)(row + stepi - 15) * H + d];
                float sold = Out[(size_t)row * H + d];
                float v = fmaxf(g * (inp + cand) + (1.f - g) * sold, 0.f);
                Out[(size_t)row * H + d] = v;
                Snext[(size_t)row * H + d] = (f16)v;
            }
        }
    }
}

extern "C" void kernel_launch(void* const* d_in, const int* in_sizes, int n_in,
                              void* d_out, int out_size, void* d_ws, size_t ws_size,
                              hipStream_t stream) {
    (void)in_sizes; (void)n_in; (void)out_size; (void)ws_size;
    const float* x  = (const float*)d_in[0];
    const float* Wx = (const float*)d_in[1];
    const float* Wy = (const float*)d_in[2];
    const float* by = (const float*)d_in[3];
    float* out = (float*)d_out;

    char* ws = (char*)d_ws;
    const size_t MB = 1024ull * 1024ull;
    f16* st16a = (f16*)(ws);             // 32 MiB: x_f16 during proj, then state ping
    f16* st16b = (f16*)(ws + 32 * MB);   // 32 MiB: state pong
    f16* P16   = (f16*)(ws + 64 * MB);   // 32 MiB: projection, fp16
    f16* WxT   = (f16*)(ws + 96 * MB);   // 2 MiB
    f16* WyT   = (f16*)(ws + 98 * MB);   // 4 MiB
    // total ws use: 102 MiB

    // x -> fp16
    hipLaunchKernelGGL(k_f32_to_f16, dim3(MROWS * H / 8 / 256), dim3(256), 0, stream, x, st16a);
    // weight transposes (fp16)
    hipLaunchKernelGGL(k_transpose_f16, dim3(H / 32, H / 32), dim3(32, 8), 0, stream, Wx, WxT, H, H);
    hipLaunchKernelGGL(k_transpose_f16, dim3(2 * H / 32, H / 32), dim3(32, 8), 0, stream, Wy, WyT, H, 2 * H);
    // P = x @ Wx  (fp16 out)
    hipLaunchKernelGGL(k_proj_gemm, dim3(MROWS / 128, H / 128), dim3(256), 0, stream, st16a, WxT, P16);
    // step 0 (state==0)
    hipLaunchKernelGGL(k_step0, dim3(MROWS * H / 4 / 256), dim3(256), 0, stream, P16, by, out, st16b);
    // steps 1..15
    f16* bufs[2] = {st16a, st16b};
    for (int i = 1; i <= 15; ++i) {
        const f16* cur = bufs[i & 1];
        f16* nxt = bufs[(i + 1) & 1];
        hipLaunchKernelGGL(k_step_gemm, dim3(MROWS / 128, 16), dim3(256), 0, stream,
                           cur, WyT, P16, by, out, nxt, i);
    }
}

// Round 4
// 1466.921 us; speedup vs baseline: 1.7623x; 1.7623x over previous
//
#include <hip/hip_runtime.h>

#define H 1024
#define SEQ 2048
#define MROWS 16384           // 8 * 2048
#define KD 1024               // GEMM K dim
#define LDSW 72               // padded f16 row stride for epilogue staging

typedef _Float16 f16;
typedef _Float16 f16x8 __attribute__((ext_vector_type(8)));
typedef float f32x4 __attribute__((ext_vector_type(4)));

__device__ __forceinline__ float gate_fn(float x) {
    float s = 1.0f / (1.0f + __expf(-x));
    return fminf(fmaxf(1.2f * s - 0.1f, 0.0f), 1.0f);
}

__device__ __forceinline__ void gload_lds16(const void* g, void* lds) {
    __builtin_amdgcn_global_load_lds(
        (const __attribute__((address_space(1))) unsigned int*)g,
        (__attribute__((address_space(3))) unsigned int*)lds, 16, 0, 0);
}

// ---------------- fp32 -> fp16 convert (8 elems/thread) ----------------
__global__ void k_f32_to_f16(const float* __restrict__ in, f16* __restrict__ out) {
    size_t i = ((size_t)blockIdx.x * blockDim.x + threadIdx.x) * 8;
    float4 v0 = *(const float4*)(in + i);
    float4 v1 = *(const float4*)(in + i + 4);
    f16x8 o;
    o[0] = (f16)v0.x; o[1] = (f16)v0.y; o[2] = (f16)v0.z; o[3] = (f16)v0.w;
    o[4] = (f16)v1.x; o[5] = (f16)v1.y; o[6] = (f16)v1.z; o[7] = (f16)v1.w;
    *(f16x8*)(out + i) = o;
}

// ---------------- transpose + convert: WT[n][k] = (f16)W[k][n] ----------------
__global__ void k_transpose_f16(const float* __restrict__ Wsrc, f16* __restrict__ WT,
                                int K, int N) {
    __shared__ float tile[32][33];
    int n0 = blockIdx.x * 32, k0 = blockIdx.y * 32;
    for (int i = threadIdx.y; i < 32; i += 8)
        tile[i][threadIdx.x] = Wsrc[(size_t)(k0 + i) * N + n0 + threadIdx.x];
    __syncthreads();
    for (int i = threadIdx.y; i < 32; i += 8)
        WT[(size_t)(n0 + i) * K + k0 + threadIdx.x] = (f16)tile[threadIdx.x][i];
}

// ---------------- proj GEMM: P16 = (f16)(A @ BT^T) ----------------
__global__ __launch_bounds__(256) void k_proj_gemm(const f16* __restrict__ A,
                                                   const f16* __restrict__ BT,
                                                   f16* __restrict__ P16) {
    __shared__ alignas(16) f16 Alds[128 * 32];
    __shared__ alignas(16) f16 Blds[128 * 32];
    const int tid = threadIdx.x;
    const int lane = tid & 63, wid = tid >> 6;
    const int l15 = lane & 15, l4 = lane >> 4;
    const int bm = blockIdx.x, bn = blockIdx.y;

    const f16* gA[2]; const f16* gB[2];
    char* ldsA[2]; char* ldsB[2];
#pragma unroll
    for (int it = 0; it < 2; ++it) {
        int c = it * 4 + wid;
        int row = c * 16 + (lane >> 2);
        int kch = (lane & 3) ^ ((row >> 1) & 3);     // pre-swizzled global source
        gA[it] = A + (size_t)(bm * 128 + row) * KD + kch * 8;
        gB[it] = BT + (size_t)(bn * 128 + row) * KD + kch * 8;
        ldsA[it] = (char*)Alds + c * 1024;           // wave-uniform LDS base
        ldsB[it] = (char*)Blds + c * 1024;
    }

    int offA[2], offB[8];
#pragma unroll
    for (int m = 0; m < 2; ++m) {
        int row = wid * 32 + m * 16 + l15;
        offA[m] = row * 64 + ((l4 ^ ((row >> 1) & 3)) << 4);
    }
#pragma unroll
    for (int n = 0; n < 8; ++n) {
        int row = n * 16 + l15;
        offB[n] = row * 64 + ((l4 ^ ((row >> 1) & 3)) << 4);
    }

    f32x4 acc[2][8] = {};

    for (int kt = 0; kt < KD / 32; ++kt) {
        __syncthreads();
#pragma unroll
        for (int it = 0; it < 2; ++it) {
            gload_lds16(gA[it], ldsA[it]);
            gload_lds16(gB[it], ldsB[it]);
            gA[it] += 32; gB[it] += 32;
        }
        __syncthreads();
        f16x8 a[2], b[8];
#pragma unroll
        for (int m = 0; m < 2; ++m) a[m] = *(const f16x8*)((const char*)Alds + offA[m]);
#pragma unroll
        for (int n = 0; n < 8; ++n) b[n] = *(const f16x8*)((const char*)Blds + offB[n]);
#pragma unroll
        for (int n = 0; n < 8; ++n)
#pragma unroll
            for (int m = 0; m < 2; ++m)
                acc[m][n] = __builtin_amdgcn_mfma_f32_16x16x32_f16(a[m], b[n], acc[m][n], 0, 0, 0);
    }

#pragma unroll
    for (int m = 0; m < 2; ++m)
#pragma unroll
        for (int n = 0; n < 8; ++n) {
            int col = bn * 128 + n * 16 + l15;
#pragma unroll
            for (int r = 0; r < 4; ++r) {
                int row = bm * 128 + wid * 32 + m * 16 + l4 * 4 + r;
                P16[(size_t)row * H + col] = (f16)acc[m][n][r];
            }
        }
}

// ---------------- step 0 (state==0): elementwise, f16 state only ----------------
__global__ void k_step0(const f16* __restrict__ P16, const float* __restrict__ by,
                        f16* __restrict__ S16) {
    size_t idx = ((size_t)blockIdx.x * blockDim.x + threadIdx.x) * 8;
    int row = (int)(idx >> 10);
    int d = (int)(idx & 1023);
    int s = row & (SEQ - 1);
    f16x8 p = {};
    if (s >= 15) p = *(const f16x8*)(P16 + (size_t)(row - 15) * H + d);
    float4 byc0 = *(const float4*)(by + d);
    float4 byc1 = *(const float4*)(by + d + 4);
    float4 byg0 = *(const float4*)(by + H + d);
    float4 byg1 = *(const float4*)(by + H + d + 4);
    f16x8 sv;
#pragma unroll
    for (int j = 0; j < 8; ++j) {
        float byc = (j < 4) ? ((const float*)&byc0)[j] : ((const float*)&byc1)[j - 4];
        float byg = (j < 4) ? ((const float*)&byg0)[j] : ((const float*)&byg1)[j - 4];
        float g = gate_fn(byg);
        float v = fmaxf(g * ((float)p[j] + byc), 0.f);
        sv[j] = (f16)v;
    }
    *(f16x8*)(S16 + idx) = sv;
}

// ---------------- step GEMM + fused gate/relu epilogue (two-phase) ----------------
// A = state_f16 [M][K]; BT = WyT [2H][K]. Block computes ns rows bm*128..+128,
// cols {cand: t*64..+64, gate: 1024+t*64..+64}; writes f16 next-state tile,
// and on the last step also fp32 Out.
__global__ __launch_bounds__(256) void k_step_gemm(const f16* __restrict__ A,
                                                   const f16* __restrict__ BT,
                                                   const f16* __restrict__ P16,
                                                   const float* __restrict__ by,
                                                   float* __restrict__ Out,
                                                   f16* __restrict__ Snext,
                                                   int stepi) {
    __shared__ alignas(16) char ldsraw[2 * 128 * LDSW * 2];  // 36 KiB (union)
    f16* Alds = (f16*)ldsraw;                                 // GEMM: 8 KiB
    f16* Blds = (f16*)(ldsraw + 8192);                        // GEMM: 8 KiB
    f16* Cand = (f16*)ldsraw;                                 // epilogue: 18 KiB
    f16* Gate = (f16*)(ldsraw + 128 * LDSW * 2);              // epilogue: 18 KiB

    const int tid = threadIdx.x;
    const int lane = tid & 63, wid = tid >> 6;
    const int l15 = lane & 15, l4 = lane >> 4;

    // bijective XCD swizzle: each XCD gets a contiguous wg chunk; t fastest
    const int nwg = gridDim.x;                 // 2048, %8==0
    const int orig = blockIdx.x;
    const int wg = (orig & 7) * (nwg >> 3) + (orig >> 3);
    const int t = wg & 15;
    const int bm = wg >> 4;

    const f16* gA[2]; const f16* gB[2];
    char* ldsA[2]; char* ldsB[2];
#pragma unroll
    for (int it = 0; it < 2; ++it) {
        int c = it * 4 + wid;
        int row = c * 16 + (lane >> 2);
        int kch = (lane & 3) ^ ((row >> 1) & 3);
        gA[it] = A + (size_t)(bm * 128 + row) * KD + kch * 8;
        int rowB = t * 64 + row + (row >= 64 ? 960 : 0);  // cand rows then gate rows
        gB[it] = BT + (size_t)rowB * KD + kch * 8;
        ldsA[it] = (char*)Alds + c * 1024;
        ldsB[it] = (char*)Blds + c * 1024;
    }

    int offA[2], offB[8];
#pragma unroll
    for (int m = 0; m < 2; ++m) {
        int row = wid * 32 + m * 16 + l15;
        offA[m] = row * 64 + ((l4 ^ ((row >> 1) & 3)) << 4);
    }
#pragma unroll
    for (int n = 0; n < 8; ++n) {
        int row = n * 16 + l15;
        offB[n] = row * 64 + ((l4 ^ ((row >> 1) & 3)) << 4);
    }

    f32x4 acc[2][8] = {};

    for (int kt = 0; kt < KD / 32; ++kt) {
        __syncthreads();
#pragma unroll
        for (int it = 0; it < 2; ++it) {
            gload_lds16(gA[it], ldsA[it]);
            gload_lds16(gB[it], ldsB[it]);
            gA[it] += 32; gB[it] += 32;
        }
        __syncthreads();
        f16x8 a[2], b[8];
#pragma unroll
        for (int m = 0; m < 2; ++m) a[m] = *(const f16x8*)((const char*)Alds + offA[m]);
#pragma unroll
        for (int n = 0; n < 8; ++n) b[n] = *(const f16x8*)((const char*)Blds + offB[n]);
#pragma unroll
        for (int n = 0; n < 8; ++n)
#pragma unroll
            for (int m = 0; m < 2; ++m)
                acc[m][n] = __builtin_amdgcn_mfma_f32_16x16x32_f16(a[m], b[n], acc[m][n], 0, 0, 0);
    }

    // ---- phase 1: stage raw accumulators (f16) into padded LDS tiles ----
    __syncthreads();   // all waves done with GEMM LDS
#pragma unroll
    for (int m = 0; m < 2; ++m)
#pragma unroll
        for (int n = 0; n < 4; ++n)
#pragma unroll
            for (int r = 0; r < 4; ++r) {
                int row = wid * 32 + m * 16 + l4 * 4 + r;
                int col = n * 16 + l15;
                Cand[row * LDSW + col] = (f16)acc[m][n][r];
                Gate[row * LDSW + col] = (f16)acc[m][n + 4][r];
            }
    __syncthreads();

    // ---- phase 2: vectorized elementwise update (16B/lane everywhere) ----
    const bool last = (stepi == 15);
    const int rl0 = tid >> 3;         // 0..31
    const int dl = (tid & 7) * 8;     // 0..56
    const int dg = t * 64 + dl;
    float4 byc0 = *(const float4*)(by + dg);
    float4 byc1 = *(const float4*)(by + dg + 4);
    float4 byg0 = *(const float4*)(by + H + dg);
    float4 byg1 = *(const float4*)(by + H + dg + 4);
#pragma unroll
    for (int p = 0; p < 4; ++p) {
        int rl = p * 32 + rl0;
        int grow = bm * 128 + rl;
        int s = grow & (SEQ - 1);
        f16x8 c8 = *(const f16x8*)(Cand + rl * LDSW + dl);
        f16x8 g8 = *(const f16x8*)(Gate + rl * LDSW + dl);
        f16x8 p8 = {};
        if (s >= 15 - stepi)
            p8 = *(const f16x8*)(P16 + (size_t)(grow + stepi - 15) * H + dg);
        f16x8 s8 = *(const f16x8*)(A + (size_t)grow * H + dg);   // old state, L2-hot
        f16x8 o8;
        float ov[8];
#pragma unroll
        for (int j = 0; j < 8; ++j) {
            float byc = (j < 4) ? ((const float*)&byc0)[j] : ((const float*)&byc1)[j - 4];
            float byg = (j < 4) ? ((const float*)&byg0)[j] : ((const float*)&byg1)[j - 4];
            float cand = (float)c8[j] + byc;
            float g = gate_fn((float)g8[j] + byg);
            float v = fmaxf(g * ((float)p8[j] + cand) + (1.f - g) * (float)s8[j], 0.f);
            o8[j] = (f16)v;
            ov[j] = v;
        }
        *(f16x8*)(Snext + (size_t)grow * H + dg) = o8;
        if (last) {
            float4 w0 = make_float4(ov[0], ov[1], ov[2], ov[3]);
            float4 w1 = make_float4(ov[4], ov[5], ov[6], ov[7]);
            *(float4*)(Out + (size_t)grow * H + dg) = w0;
            *(float4*)(Out + (size_t)grow * H + dg + 4) = w1;
        }
    }
}

extern "C" void kernel_launch(void* const* d_in, const int* in_sizes, int n_in,
                              void* d_out, int out_size, void* d_ws, size_t ws_size,
                              hipStream_t stream) {
    (void)in_sizes; (void)n_in; (void)out_size; (void)ws_size;
    const float* x  = (const float*)d_in[0];
    const float* Wx = (const float*)d_in[1];
    const float* Wy = (const float*)d_in[2];
    const float* by = (const float*)d_in[3];
    float* out = (float*)d_out;

    char* ws = (char*)d_ws;
    const size_t MB = 1024ull * 1024ull;
    f16* st16a = (f16*)(ws);             // 32 MiB: x_f16 during proj, then state ping
    f16* st16b = (f16*)(ws + 32 * MB);   // 32 MiB: state pong
    f16* P16   = (f16*)(ws + 64 * MB);   // 32 MiB: projection, fp16
    f16* WxT   = (f16*)(ws + 96 * MB);   // 2 MiB
    f16* WyT   = (f16*)(ws + 98 * MB);   // 4 MiB

    // x -> fp16
    hipLaunchKernelGGL(k_f32_to_f16, dim3(MROWS * H / 8 / 256), dim3(256), 0, stream, x, st16a);
    // weight transposes (fp16)
    hipLaunchKernelGGL(k_transpose_f16, dim3(H / 32, H / 32), dim3(32, 8), 0, stream, Wx, WxT, H, H);
    hipLaunchKernelGGL(k_transpose_f16, dim3(2 * H / 32, H / 32), dim3(32, 8), 0, stream, Wy, WyT, H, 2 * H);
    // P = x @ Wx  (fp16 out)
    hipLaunchKernelGGL(k_proj_gemm, dim3(MROWS / 128, H / 128), dim3(256), 0, stream, st16a, WxT, P16);
    // step 0 (state==0)
    hipLaunchKernelGGL(k_step0, dim3(MROWS * H / 8 / 256), dim3(256), 0, stream, P16, by, st16b);
    // steps 1..15 (last one also writes fp32 Out)
    f16* bufs[2] = {st16a, st16b};
    for (int i = 1; i <= 15; ++i) {
        const f16* cur = bufs[i & 1];
        f16* nxt = bufs[(i + 1) & 1];
        hipLaunchKernelGGL(k_step_gemm, dim3(MROWS / 128 * 16), dim3(256), 0, stream,
                           cur, WyT, P16, by, out, nxt, i);
    }
}

// Round 5
// 1386.517 us; speedup vs baseline: 1.8645x; 1.0580x over previous
//
#include <hip/hip_runtime.h>

#define H 1024
#define SEQ 2048
#define MROWS 16384           // 8 * 2048
#define KD 1024               // GEMM K dim
#define BK 32
#define NT (KD / BK)          // 32 K-tiles
#define EPW 72                // epilogue LDS stride (f16)
#define LDSW 72               // 128^2 kernel epilogue stride

typedef _Float16 f16;
typedef _Float16 f16x8 __attribute__((ext_vector_type(8)));
typedef float f32x4 __attribute__((ext_vector_type(4)));

__device__ __forceinline__ float gate_fn(float x) {
    float s = 1.0f / (1.0f + __expf(-x));
    return fminf(fmaxf(1.2f * s - 0.1f, 0.0f), 1.0f);
}

__device__ __forceinline__ void gload_lds16(const void* g, void* lds) {
    __builtin_amdgcn_global_load_lds(
        (const __attribute__((address_space(1))) unsigned int*)g,
        (__attribute__((address_space(3))) unsigned int*)lds, 16, 0, 0);
}

// ---------------- fp32 -> fp16 convert ----------------
__global__ void k_f32_to_f16(const float* __restrict__ in, f16* __restrict__ out) {
    size_t i = ((size_t)blockIdx.x * blockDim.x + threadIdx.x) * 8;
    float4 v0 = *(const float4*)(in + i);
    float4 v1 = *(const float4*)(in + i + 4);
    f16x8 o;
    o[0] = (f16)v0.x; o[1] = (f16)v0.y; o[2] = (f16)v0.z; o[3] = (f16)v0.w;
    o[4] = (f16)v1.x; o[5] = (f16)v1.y; o[6] = (f16)v1.z; o[7] = (f16)v1.w;
    *(f16x8*)(out + i) = o;
}

// ---------------- transpose + convert: WT[n][k] = (f16)W[k][n] ----------------
__global__ void k_transpose_f16(const float* __restrict__ Wsrc, f16* __restrict__ WT,
                                int K, int N) {
    __shared__ float tile[32][33];
    int n0 = blockIdx.x * 32, k0 = blockIdx.y * 32;
    for (int i = threadIdx.y; i < 32; i += 8)
        tile[i][threadIdx.x] = Wsrc[(size_t)(k0 + i) * N + n0 + threadIdx.x];
    __syncthreads();
    for (int i = threadIdx.y; i < 32; i += 8)
        WT[(size_t)(n0 + i) * K + k0 + threadIdx.x] = (f16)tile[threadIdx.x][i];
}

// ---------------- proj GEMM (128x128, unchanged from R4) ----------------
__global__ __launch_bounds__(256) void k_proj_gemm(const f16* __restrict__ A,
                                                   const f16* __restrict__ BT,
                                                   f16* __restrict__ P16) {
    __shared__ alignas(16) f16 Alds[128 * 32];
    __shared__ alignas(16) f16 Blds[128 * 32];
    const int tid = threadIdx.x;
    const int lane = tid & 63, wid = tid >> 6;
    const int l15 = lane & 15, l4 = lane >> 4;
    const int bm = blockIdx.x, bn = blockIdx.y;

    const f16* gA[2]; const f16* gB[2];
    char* ldsA[2]; char* ldsB[2];
#pragma unroll
    for (int it = 0; it < 2; ++it) {
        int c = it * 4 + wid;
        int row = c * 16 + (lane >> 2);
        int kch = (lane & 3) ^ ((row >> 1) & 3);
        gA[it] = A + (size_t)(bm * 128 + row) * KD + kch * 8;
        gB[it] = BT + (size_t)(bn * 128 + row) * KD + kch * 8;
        ldsA[it] = (char*)Alds + c * 1024;
        ldsB[it] = (char*)Blds + c * 1024;
    }

    int offA[2], offB[8];
#pragma unroll
    for (int m = 0; m < 2; ++m) {
        int row = wid * 32 + m * 16 + l15;
        offA[m] = row * 64 + ((l4 ^ ((row >> 1) & 3)) << 4);
    }
#pragma unroll
    for (int n = 0; n < 8; ++n) {
        int row = n * 16 + l15;
        offB[n] = row * 64 + ((l4 ^ ((row >> 1) & 3)) << 4);
    }

    f32x4 acc[2][8] = {};

    for (int kt = 0; kt < KD / 32; ++kt) {
        __syncthreads();
#pragma unroll
        for (int it = 0; it < 2; ++it) {
            gload_lds16(gA[it], ldsA[it]);
            gload_lds16(gB[it], ldsB[it]);
            gA[it] += 32; gB[it] += 32;
        }
        __syncthreads();
        f16x8 a[2], b[8];
#pragma unroll
        for (int m = 0; m < 2; ++m) a[m] = *(const f16x8*)((const char*)Alds + offA[m]);
#pragma unroll
        for (int n = 0; n < 8; ++n) b[n] = *(const f16x8*)((const char*)Blds + offB[n]);
#pragma unroll
        for (int n = 0; n < 8; ++n)
#pragma unroll
            for (int m = 0; m < 2; ++m)
                acc[m][n] = __builtin_amdgcn_mfma_f32_16x16x32_f16(a[m], b[n], acc[m][n], 0, 0, 0);
    }

#pragma unroll
    for (int m = 0; m < 2; ++m)
#pragma unroll
        for (int n = 0; n < 8; ++n) {
            int col = bn * 128 + n * 16 + l15;
#pragma unroll
            for (int r = 0; r < 4; ++r) {
                int row = bm * 128 + wid * 32 + m * 16 + l4 * 4 + r;
                P16[(size_t)row * H + col] = (f16)acc[m][n][r];
            }
        }
}

// ---------------- step 0 (state==0) ----------------
__global__ void k_step0(const f16* __restrict__ P16, const float* __restrict__ by,
                        f16* __restrict__ S16) {
    size_t idx = ((size_t)blockIdx.x * blockDim.x + threadIdx.x) * 8;
    int row = (int)(idx >> 10);
    int d = (int)(idx & 1023);
    int s = row & (SEQ - 1);
    f16x8 p = {};
    if (s >= 15) p = *(const f16x8*)(P16 + (size_t)(row - 15) * H + d);
    float4 byc0 = *(const float4*)(by + d);
    float4 byc1 = *(const float4*)(by + d + 4);
    float4 byg0 = *(const float4*)(by + H + d);
    float4 byg1 = *(const float4*)(by + H + d + 4);
    f16x8 sv;
#pragma unroll
    for (int j = 0; j < 8; ++j) {
        float byc = (j < 4) ? ((const float*)&byc0)[j] : ((const float*)&byc1)[j - 4];
        float byg = (j < 4) ? ((const float*)&byg0)[j] : ((const float*)&byg1)[j - 4];
        float g = gate_fn(byg);
        float v = fmaxf(g * ((float)p[j] + byc), 0.f);
        sv[j] = (f16)v;
    }
    *(f16x8*)(S16 + idx) = sv;
}

// ---------------- step GEMM 256x256, 3-buffer counted-vmcnt pipeline ----------------
// A = state_f16 [M][K]; BT = WyT [2H][K]. Block bm,nb computes rows bm*256..+256,
// cand cols nb*128..+128 + their gates. B-tile row r (0..255) -> WyT row
// ((r>>5)&1)*H + nb*128 + (r>>6)*32 + (r&31)  (32-row cand/gate interleave so
// pairing is in-thread: acc[m][n] cand, acc[m][n+2] gate).
__global__ __launch_bounds__(512) void k_step_gemm256(const f16* __restrict__ A,
                                                      const f16* __restrict__ BT,
                                                      const f16* __restrict__ P16,
                                                      const float* __restrict__ by,
                                                      float* __restrict__ Out,
                                                      f16* __restrict__ Snext,
                                                      int stepi) {
    __shared__ alignas(16) char lds[98304];   // 3 x (16 KiB A + 16 KiB B); epilogue reuses
    const int tid = threadIdx.x;
    const int lane = tid & 63, w = tid >> 6;
    const int l15 = lane & 15, l4 = lane >> 4;
    const int wr = w >> 2, wc = w & 3;

    // XCD swizzle: 512 wgs, 64 per XCD; nb fastest so one A-panel per 8 blocks
    const int orig = blockIdx.x;
    const int wg = (orig & 7) * 64 + (orig >> 3);
    const int bm = wg >> 3, nb = wg & 7;

    // staging source pointers (per-lane, pre-swizzled), at kt=0
    const int rA0 = w * 16 + (lane >> 2);       // tile row 0..127
    const int rA1 = rA0 + 128;                  // 128..255
    const char* pA0 = (const char*)A + ((size_t)(bm * 256 + rA0) * KD + (((lane & 3) ^ ((rA0 >> 1) & 3)) * 8)) * 2;
    const char* pA1 = (const char*)A + ((size_t)(bm * 256 + rA1) * KD + (((lane & 3) ^ ((rA1 >> 1) & 3)) * 8)) * 2;
    const int gB0 = ((rA0 >> 5) & 1) * H + nb * 128 + (rA0 >> 6) * 32 + (rA0 & 31);
    const int gB1 = ((rA1 >> 5) & 1) * H + nb * 128 + (rA1 >> 6) * 32 + (rA1 & 31);
    const char* pB0 = (const char*)BT + ((size_t)gB0 * KD + (((lane & 3) ^ ((rA0 >> 1) & 3)) * 8)) * 2;
    const char* pB1 = (const char*)BT + ((size_t)gB1 * KD + (((lane & 3) ^ ((rA1 >> 1) & 3)) * 8)) * 2;

    const int dstoff = w * 1024 + lane * 16;
    char* cb = lds;                 // compute buf (tile t)
    char* nbuf = lds + 32768;       // next (tile t+1)
    char* sb = lds + 65536;         // stage dest (tile t+2)

#define STAGE_TILE(lb) do {                                  \
        gload_lds16(pA0, (lb) + dstoff);                     \
        gload_lds16(pA1, (lb) + 8192 + dstoff);              \
        gload_lds16(pB0, (lb) + 16384 + dstoff);             \
        gload_lds16(pB1, (lb) + 24576 + dstoff);             \
        pA0 += 64; pA1 += 64; pB0 += 64; pB1 += 64; } while (0)

    // ds_read offsets (swizzled); (row>>1)&3 == (l15>>1)&3 since frag rows are
    // base16 + l15
    const int sx = (l4 ^ ((l15 >> 1) & 3)) << 4;
    int offA[8], offB[4];
#pragma unroll
    for (int m = 0; m < 8; ++m) offA[m] = (wr * 128 + m * 16 + l15) * 64 + sx;
#pragma unroll
    for (int n = 0; n < 4; ++n) offB[n] = (wc * 64 + n * 16 + l15) * 64 + sx;

    f32x4 acc[8][4] = {};

    // prologue: stage tiles 0,1; wait tile 0
    STAGE_TILE(cb);
    STAGE_TILE(nbuf);
    asm volatile("s_waitcnt vmcnt(4)" ::: "memory");
    __builtin_amdgcn_sched_barrier(0);
    __syncthreads();

    for (int t = 0; t < NT; ++t) {
        if (t + 2 < NT) STAGE_TILE(sb);
        f16x8 a[8], b[4];
#pragma unroll
        for (int m = 0; m < 8; ++m) a[m] = *(const f16x8*)(cb + offA[m]);
#pragma unroll
        for (int n = 0; n < 4; ++n) b[n] = *(const f16x8*)(cb + 16384 + offB[n]);
        __builtin_amdgcn_s_setprio(1);
#pragma unroll
        for (int m = 0; m < 8; ++m)
#pragma unroll
            for (int n = 0; n < 4; ++n)
                acc[m][n] = __builtin_amdgcn_mfma_f32_16x16x32_f16(a[m], b[n], acc[m][n], 0, 0, 0);
        __builtin_amdgcn_s_setprio(0);
        if (t + 2 < NT) { asm volatile("s_waitcnt vmcnt(4)" ::: "memory"); }
        else           { asm volatile("s_waitcnt vmcnt(0)" ::: "memory"); }
        __builtin_amdgcn_sched_barrier(0);
        __syncthreads();
        char* tmp = cb; cb = nbuf; nbuf = sb; sb = tmp;
    }

    // ---- fused epilogue: two 64-col rounds through padded LDS ----
    const bool last = (stepi == 15);
    f16* Cand = (f16*)lds;
    f16* Gate = (f16*)(lds + 256 * EPW * 2);   // ends at 73728 < 98304
#pragma unroll
    for (int rnd = 0; rnd < 2; ++rnd) {
        // phase 1: stage this round's cand/gate accumulators
#pragma unroll
        for (int m = 0; m < 8; ++m)
#pragma unroll
            for (int r4 = 0; r4 < 4; ++r4) {
                int row = wr * 128 + m * 16 + l4 * 4 + r4;
                int cr = wc * 16 + l15;
                Cand[row * EPW + cr] = (f16)acc[m][rnd][r4];
                Gate[row * EPW + cr] = (f16)acc[m][rnd + 2][r4];
            }
        __syncthreads();
        // phase 2: vectorized elementwise update
        const int g = tid & 7;
        const int rb = tid >> 3;                       // 0..63
        const int ctile = (g >> 1) * 32 + rnd * 16 + (g & 1) * 8;
        const int d = nb * 128 + ctile;
        const int cr0 = g * 8;
        float4 byc0 = *(const float4*)(by + d);
        float4 byc1 = *(const float4*)(by + d + 4);
        float4 byg0 = *(const float4*)(by + H + d);
        float4 byg1 = *(const float4*)(by + H + d + 4);
#pragma unroll
        for (int p = 0; p < 4; ++p) {
            int row = p * 64 + rb;
            int grow = bm * 256 + row;
            int s = grow & (SEQ - 1);
            f16x8 c8 = *(const f16x8*)(Cand + row * EPW + cr0);
            f16x8 g8 = *(const f16x8*)(Gate + row * EPW + cr0);
            f16x8 p8 = {};
            if (s >= 15 - stepi)
                p8 = *(const f16x8*)(P16 + (size_t)(grow + stepi - 15) * H + d);
            f16x8 s8 = *(const f16x8*)(A + (size_t)grow * H + d);
            f16x8 o8; float ov[8];
#pragma unroll
            for (int j = 0; j < 8; ++j) {
                float byc = (j < 4) ? ((const float*)&byc0)[j] : ((const float*)&byc1)[j - 4];
                float byg = (j < 4) ? ((const float*)&byg0)[j] : ((const float*)&byg1)[j - 4];
                float cand = (float)c8[j] + byc;
                float gg = gate_fn((float)g8[j] + byg);
                float v = fmaxf(gg * ((float)p8[j] + cand) + (1.f - gg) * (float)s8[j], 0.f);
                o8[j] = (f16)v; ov[j] = v;
            }
            if (!last) {
                *(f16x8*)(Snext + (size_t)grow * H + d) = o8;
            } else {
                *(float4*)(Out + (size_t)grow * H + d) = make_float4(ov[0], ov[1], ov[2], ov[3]);
                *(float4*)(Out + (size_t)grow * H + d + 4) = make_float4(ov[4], ov[5], ov[6], ov[7]);
            }
        }
        __syncthreads();   // staging reused by next round
    }
#undef STAGE_TILE
}

extern "C" void kernel_launch(void* const* d_in, const int* in_sizes, int n_in,
                              void* d_out, int out_size, void* d_ws, size_t ws_size,
                              hipStream_t stream) {
    (void)in_sizes; (void)n_in; (void)out_size; (void)ws_size;
    const float* x  = (const float*)d_in[0];
    const float* Wx = (const float*)d_in[1];
    const float* Wy = (const float*)d_in[2];
    const float* by = (const float*)d_in[3];
    float* out = (float*)d_out;

    char* ws = (char*)d_ws;
    const size_t MB = 1024ull * 1024ull;
    f16* st16a = (f16*)(ws);             // 32 MiB: x_f16 during proj, then state ping
    f16* st16b = (f16*)(ws + 32 * MB);   // 32 MiB: state pong
    f16* P16   = (f16*)(ws + 64 * MB);   // 32 MiB: projection, fp16
    f16* WxT   = (f16*)(ws + 96 * MB);   // 2 MiB
    f16* WyT   = (f16*)(ws + 98 * MB);   // 4 MiB

    hipLaunchKernelGGL(k_f32_to_f16, dim3(MROWS * H / 8 / 256), dim3(256), 0, stream, x, st16a);
    hipLaunchKernelGGL(k_transpose_f16, dim3(H / 32, H / 32), dim3(32, 8), 0, stream, Wx, WxT, H, H);
    hipLaunchKernelGGL(k_transpose_f16, dim3(2 * H / 32, H / 32), dim3(32, 8), 0, stream, Wy, WyT, H, 2 * H);
    hipLaunchKernelGGL(k_proj_gemm, dim3(MROWS / 128, H / 128), dim3(256), 0, stream, st16a, WxT, P16);
    hipLaunchKernelGGL(k_step0, dim3(MROWS * H / 8 / 256), dim3(256), 0, stream, P16, by, st16b);

    f16* bufs[2] = {st16a, st16b};
    for (int i = 1; i <= 15; ++i) {
        const f16* cur = bufs[i & 1];
        f16* nxt = bufs[(i + 1) & 1];
        hipLaunchKernelGGL(k_step_gemm256, dim3(MROWS / 256 * 8), dim3(512), 0, stream,
                           cur, WyT, P16, by, out, nxt, i);
    }
}

// Round 6
// 1329.169 us; speedup vs baseline: 1.9450x; 1.0431x over previous
//
#include <hip/hip_runtime.h>

#define H 1024
#define SEQ 2048
#define MROWS 16384           // 8 * 2048
#define KD 1024               // GEMM K dim
#define NTK 16                // K-steps of 64
#define EPW 72                // epilogue LDS stride (f16)

typedef _Float16 f16;
typedef _Float16 f16x8 __attribute__((ext_vector_type(8)));
typedef float f32x4 __attribute__((ext_vector_type(4)));

__device__ __forceinline__ float gate_fn(float x) {
    float s = 1.0f / (1.0f + __expf(-x));
    return fminf(fmaxf(1.2f * s - 0.1f, 0.0f), 1.0f);
}

__device__ __forceinline__ void gload_lds16(const void* g, void* lds) {
    __builtin_amdgcn_global_load_lds(
        (const __attribute__((address_space(1))) unsigned int*)g,
        (__attribute__((address_space(3))) unsigned int*)lds, 16, 0, 0);
}

// ---------------- fp32 -> fp16 convert ----------------
__global__ void k_f32_to_f16(const float* __restrict__ in, f16* __restrict__ out) {
    size_t i = ((size_t)blockIdx.x * blockDim.x + threadIdx.x) * 8;
    float4 v0 = *(const float4*)(in + i);
    float4 v1 = *(const float4*)(in + i + 4);
    f16x8 o;
    o[0] = (f16)v0.x; o[1] = (f16)v0.y; o[2] = (f16)v0.z; o[3] = (f16)v0.w;
    o[4] = (f16)v1.x; o[5] = (f16)v1.y; o[6] = (f16)v1.z; o[7] = (f16)v1.w;
    *(f16x8*)(out + i) = o;
}

// ---------------- transpose + convert: WT[n][k] = (f16)W[k][n] ----------------
__global__ void k_transpose_f16(const float* __restrict__ Wsrc, f16* __restrict__ WT,
                                int K, int N) {
    __shared__ float tile[32][33];
    int n0 = blockIdx.x * 32, k0 = blockIdx.y * 32;
    for (int i = threadIdx.y; i < 32; i += 8)
        tile[i][threadIdx.x] = Wsrc[(size_t)(k0 + i) * N + n0 + threadIdx.x];
    __syncthreads();
    for (int i = threadIdx.y; i < 32; i += 8)
        WT[(size_t)(n0 + i) * K + k0 + threadIdx.x] = (f16)tile[threadIdx.x][i];
}

// ---------------- proj GEMM (128x128, unchanged) ----------------
__global__ __launch_bounds__(256) void k_proj_gemm(const f16* __restrict__ A,
                                                   const f16* __restrict__ BT,
                                                   f16* __restrict__ P16) {
    __shared__ alignas(16) f16 Alds[128 * 32];
    __shared__ alignas(16) f16 Blds[128 * 32];
    const int tid = threadIdx.x;
    const int lane = tid & 63, wid = tid >> 6;
    const int l15 = lane & 15, l4 = lane >> 4;
    const int bm = blockIdx.x, bn = blockIdx.y;

    const f16* gA[2]; const f16* gB[2];
    char* ldsA[2]; char* ldsB[2];
#pragma unroll
    for (int it = 0; it < 2; ++it) {
        int c = it * 4 + wid;
        int row = c * 16 + (lane >> 2);
        int kch = (lane & 3) ^ ((row >> 1) & 3);
        gA[it] = A + (size_t)(bm * 128 + row) * KD + kch * 8;
        gB[it] = BT + (size_t)(bn * 128 + row) * KD + kch * 8;
        ldsA[it] = (char*)Alds + c * 1024;
        ldsB[it] = (char*)Blds + c * 1024;
    }

    int offA[2], offB[8];
#pragma unroll
    for (int m = 0; m < 2; ++m) {
        int row = wid * 32 + m * 16 + l15;
        offA[m] = row * 64 + ((l4 ^ ((row >> 1) & 3)) << 4);
    }
#pragma unroll
    for (int n = 0; n < 8; ++n) {
        int row = n * 16 + l15;
        offB[n] = row * 64 + ((l4 ^ ((row >> 1) & 3)) << 4);
    }

    f32x4 acc[2][8] = {};

    for (int kt = 0; kt < KD / 32; ++kt) {
        __syncthreads();
#pragma unroll
        for (int it = 0; it < 2; ++it) {
            gload_lds16(gA[it], ldsA[it]);
            gload_lds16(gB[it], ldsB[it]);
            gA[it] += 32; gB[it] += 32;
        }
        __syncthreads();
        f16x8 a[2], b[8];
#pragma unroll
        for (int m = 0; m < 2; ++m) a[m] = *(const f16x8*)((const char*)Alds + offA[m]);
#pragma unroll
        for (int n = 0; n < 8; ++n) b[n] = *(const f16x8*)((const char*)Blds + offB[n]);
#pragma unroll
        for (int n = 0; n < 8; ++n)
#pragma unroll
            for (int m = 0; m < 2; ++m)
                acc[m][n] = __builtin_amdgcn_mfma_f32_16x16x32_f16(a[m], b[n], acc[m][n], 0, 0, 0);
    }

#pragma unroll
    for (int m = 0; m < 2; ++m)
#pragma unroll
        for (int n = 0; n < 8; ++n) {
            int col = bn * 128 + n * 16 + l15;
#pragma unroll
            for (int r = 0; r < 4; ++r) {
                int row = bm * 128 + wid * 32 + m * 16 + l4 * 4 + r;
                P16[(size_t)row * H + col] = (f16)acc[m][n][r];
            }
        }
}

// ---------------- step 0 (state==0) ----------------
__global__ void k_step0(const f16* __restrict__ P16, const float* __restrict__ by,
                        f16* __restrict__ S16) {
    size_t idx = ((size_t)blockIdx.x * blockDim.x + threadIdx.x) * 8;
    int row = (int)(idx >> 10);
    int d = (int)(idx & 1023);
    int s = row & (SEQ - 1);
    f16x8 p = {};
    if (s >= 15) p = *(const f16x8*)(P16 + (size_t)(row - 15) * H + d);
    float4 byc0 = *(const float4*)(by + d);
    float4 byc1 = *(const float4*)(by + d + 4);
    float4 byg0 = *(const float4*)(by + H + d);
    float4 byg1 = *(const float4*)(by + H + d + 4);
    f16x8 sv;
#pragma unroll
    for (int j = 0; j < 8; ++j) {
        float byc = (j < 4) ? ((const float*)&byc0)[j] : ((const float*)&byc1)[j - 4];
        float byg = (j < 4) ? ((const float*)&byg0)[j] : ((const float*)&byg1)[j - 4];
        float g = gate_fn(byg);
        float v = fmaxf(g * ((float)p[j] + byc), 0.f);
        sv[j] = (f16)v;
    }
    *(f16x8*)(S16 + idx) = sv;
}

// ---------------- step GEMM 256x256, 8-phase counted-vmcnt schedule ----------------
// A = state_f16 [M][K]; BT = WyT [2H][K]. Block (bm,cbn): rows bm*256..+256,
// cand cols cbn*128..+128 + gates, via B-tile row map
// r -> ((r>>5)&1)*H + cbn*128 + (r>>6)*32 + (r&31).
// K-step = 64 (2 k-halves of 32). 4 phases per K-step, 2 LDS dbufs of 64 KiB.
// vmcnt(4) at ph0/ph2 (2 half-tiles in flight), raw s_barrier, setprio MFMA.
__global__ __launch_bounds__(512) void k_step_gemm256(const f16* __restrict__ A,
                                                      const f16* __restrict__ BT,
                                                      const f16* __restrict__ P16,
                                                      const float* __restrict__ by,
                                                      float* __restrict__ Out,
                                                      f16* __restrict__ Snext,
                                                      int stepi) {
    __shared__ alignas(16) char lds[131072];   // 2 x (32 KiB A + 32 KiB B); epilogue reuses
    const int tid = threadIdx.x;
    const int lane = tid & 63, w = tid >> 6;
    const int l15 = lane & 15, l4 = lane >> 4;
    const int wr = w >> 2, wc = w & 3;

    // bijective XCD swizzle: 512 wgs, 64/XCD, cbn fastest (A-panel L2 reuse)
    const int orig = blockIdx.x;
    const int wg = (orig & 7) * 64 + (orig >> 3);
    const int bm = wg >> 3, cbn = wg & 7;

    // staging: half-tile = one operand x one k-half = 256 rows x 32 k = 16 KiB
    // = 2 gloads/thread (rows r0, r1). Pre-swizzled source slot.
    const int r0 = w * 16 + (lane >> 2), r1 = r0 + 128;
    const int slot = (lane & 3) ^ ((r0 >> 1) & 3);   // (r1>>1)&3 == (r0>>1)&3
    const char* pA0 = (const char*)A + ((size_t)(bm * 256 + r0) * KD + slot * 8) * 2;
    const char* pA1 = (const char*)A + ((size_t)(bm * 256 + r1) * KD + slot * 8) * 2;
    const int gB0 = ((r0 >> 5) & 1) * H + cbn * 128 + (r0 >> 6) * 32 + (r0 & 31);
    const int gB1 = ((r1 >> 5) & 1) * H + cbn * 128 + (r1 >> 6) * 32 + (r1 & 31);
    const char* pB0 = (const char*)BT + ((size_t)gB0 * KD + slot * 8) * 2;
    const char* pB1 = (const char*)BT + ((size_t)gB1 * KD + slot * 8) * 2;
    const int dst = w * 1024 + lane * 16;

    // buffer layout: [A kh0 16K][A kh1 16K][B kh0 16K][B kh1 16K] = 64 KiB
#define STA(bp, kh) do { gload_lds16(pA0 + (kh)*64, (bp) + (kh)*16384 + dst); \
                         gload_lds16(pA1 + (kh)*64, (bp) + (kh)*16384 + 8192 + dst); } while (0)
#define STB(bp, kh) do { gload_lds16(pB0 + (kh)*64, (bp) + 32768 + (kh)*16384 + dst); \
                         gload_lds16(pB1 + (kh)*64, (bp) + 32768 + (kh)*16384 + 8192 + dst); } while (0)

    const int sx = (l4 ^ ((l15 >> 1) & 3)) << 4;
    int offA[8], offB[4];
#pragma unroll
    for (int m = 0; m < 8; ++m) offA[m] = (wr * 128 + m * 16 + l15) * 64 + sx;
#pragma unroll
    for (int n = 0; n < 4; ++n) offB[n] = 32768 + (wc * 64 + n * 16 + l15) * 64 + sx;

    f32x4 acc[8][4] = {};
    f16x8 av[4], bv[4];

    char* cb = lds;
    char* nx = lds + 65536;

    // prologue: stage K-step 0 (4 half-tiles, 8 loads)
    STA(cb, 0); STB(cb, 0); STA(cb, 1); STB(cb, 1);
    pA0 += 128; pA1 += 128; pB0 += 128; pB1 += 128;

    for (int t = 0; t < NTK; ++t) {
        const bool pf = (t + 1 < NTK);
        // ---- phase 0: k-half 0, rows m0-3 ----
        if (pf) STA(nx, 0);
        asm volatile("s_waitcnt vmcnt(4)" ::: "memory");
        __builtin_amdgcn_s_barrier();
        __builtin_amdgcn_sched_barrier(0);
#pragma unroll
        for (int m = 0; m < 4; ++m) av[m] = *(const f16x8*)(cb + offA[m]);
#pragma unroll
        for (int n = 0; n < 4; ++n) bv[n] = *(const f16x8*)(cb + offB[n]);
        __builtin_amdgcn_s_setprio(1);
#pragma unroll
        for (int m = 0; m < 4; ++m)
#pragma unroll
            for (int n = 0; n < 4; ++n)
                acc[m][n] = __builtin_amdgcn_mfma_f32_16x16x32_f16(av[m], bv[n], acc[m][n], 0, 0, 0);
        __builtin_amdgcn_s_setprio(0);
        __builtin_amdgcn_sched_barrier(0);
        // ---- phase 1: k-half 0, rows m4-7 (bv reused) ----
        if (pf) STB(nx, 0);
        __builtin_amdgcn_s_barrier();
        __builtin_amdgcn_sched_barrier(0);
#pragma unroll
        for (int m = 0; m < 4; ++m) av[m] = *(const f16x8*)(cb + offA[4 + m]);
        __builtin_amdgcn_s_setprio(1);
#pragma unroll
        for (int m = 0; m < 4; ++m)
#pragma unroll
            for (int n = 0; n < 4; ++n)
                acc[4 + m][n] = __builtin_amdgcn_mfma_f32_16x16x32_f16(av[m], bv[n], acc[4 + m][n], 0, 0, 0);
        __builtin_amdgcn_s_setprio(0);
        __builtin_amdgcn_sched_barrier(0);
        // ---- phase 2: k-half 1, rows m0-3 ----
        if (pf) STA(nx, 1);
        if (pf) { asm volatile("s_waitcnt vmcnt(4)" ::: "memory"); }
        else    { asm volatile("s_waitcnt vmcnt(0)" ::: "memory"); }   // final K-step: must drain
        __builtin_amdgcn_s_barrier();
        __builtin_amdgcn_sched_barrier(0);
#pragma unroll
        for (int m = 0; m < 4; ++m) av[m] = *(const f16x8*)(cb + 16384 + offA[m]);
#pragma unroll
        for (int n = 0; n < 4; ++n) bv[n] = *(const f16x8*)(cb + 16384 + offB[n]);
        __builtin_amdgcn_s_setprio(1);
#pragma unroll
        for (int m = 0; m < 4; ++m)
#pragma unroll
            for (int n = 0; n < 4; ++n)
                acc[m][n] = __builtin_amdgcn_mfma_f32_16x16x32_f16(av[m], bv[n], acc[m][n], 0, 0, 0);
        __builtin_amdgcn_s_setprio(0);
        __builtin_amdgcn_sched_barrier(0);
        // ---- phase 3: k-half 1, rows m4-7 ----
        if (pf) STB(nx, 1);
        __builtin_amdgcn_s_barrier();
        __builtin_amdgcn_sched_barrier(0);
#pragma unroll
        for (int m = 0; m < 4; ++m) av[m] = *(const f16x8*)(cb + 16384 + offA[4 + m]);
        __builtin_amdgcn_s_setprio(1);
#pragma unroll
        for (int m = 0; m < 4; ++m)
#pragma unroll
            for (int n = 0; n < 4; ++n)
                acc[4 + m][n] = __builtin_amdgcn_mfma_f32_16x16x32_f16(av[m], bv[n], acc[4 + m][n], 0, 0, 0);
        __builtin_amdgcn_s_setprio(0);
        __builtin_amdgcn_sched_barrier(0);
        if (pf) { pA0 += 128; pA1 += 128; pB0 += 128; pB1 += 128; }
        char* tmp = cb; cb = nx; nx = tmp;
    }
    asm volatile("s_waitcnt vmcnt(0)" ::: "memory");
    __syncthreads();
#undef STA
#undef STB

    // ---- fused epilogue: two 64-col rounds through padded LDS (verified R5) ----
    const bool last = (stepi == 15);
    f16* Cand = (f16*)lds;
    f16* Gate = (f16*)(lds + 256 * EPW * 2);
#pragma unroll
    for (int rnd = 0; rnd < 2; ++rnd) {
#pragma unroll
        for (int m = 0; m < 8; ++m)
#pragma unroll
            for (int r4 = 0; r4 < 4; ++r4) {
                int row = wr * 128 + m * 16 + l4 * 4 + r4;
                int cr = wc * 16 + l15;
                Cand[row * EPW + cr] = (f16)acc[m][rnd][r4];
                Gate[row * EPW + cr] = (f16)acc[m][rnd + 2][r4];
            }
        __syncthreads();
        const int g = tid & 7;
        const int rb = tid >> 3;                       // 0..63
        const int ctile = (g >> 1) * 32 + rnd * 16 + (g & 1) * 8;
        const int d = cbn * 128 + ctile;
        const int cr0 = g * 8;
        float4 byc0 = *(const float4*)(by + d);
        float4 byc1 = *(const float4*)(by + d + 4);
        float4 byg0 = *(const float4*)(by + H + d);
        float4 byg1 = *(const float4*)(by + H + d + 4);
#pragma unroll
        for (int p = 0; p < 4; ++p) {
            int row = p * 64 + rb;
            int grow = bm * 256 + row;
            int s = grow & (SEQ - 1);
            f16x8 c8 = *(const f16x8*)(Cand + row * EPW + cr0);
            f16x8 g8 = *(const f16x8*)(Gate + row * EPW + cr0);
            f16x8 p8 = {};
            if (s >= 15 - stepi)
                p8 = *(const f16x8*)(P16 + (size_t)(grow + stepi - 15) * H + d);
            f16x8 s8 = *(const f16x8*)(A + (size_t)grow * H + d);
            f16x8 o8; float ov[8];
#pragma unroll
            for (int j = 0; j < 8; ++j) {
                float byc = (j < 4) ? ((const float*)&byc0)[j] : ((const float*)&byc1)[j - 4];
                float byg = (j < 4) ? ((const float*)&byg0)[j] : ((const float*)&byg1)[j - 4];
                float cand = (float)c8[j] + byc;
                float gg = gate_fn((float)g8[j] + byg);
                float v = fmaxf(gg * ((float)p8[j] + cand) + (1.f - gg) * (float)s8[j], 0.f);
                o8[j] = (f16)v; ov[j] = v;
            }
            if (!last) {
                *(f16x8*)(Snext + (size_t)grow * H + d) = o8;
            } else {
                *(float4*)(Out + (size_t)grow * H + d) = make_float4(ov[0], ov[1], ov[2], ov[3]);
                *(float4*)(Out + (size_t)grow * H + d + 4) = make_float4(ov[4], ov[5], ov[6], ov[7]);
            }
        }
        __syncthreads();
    }
}

extern "C" void kernel_launch(void* const* d_in, const int* in_sizes, int n_in,
                              void* d_out, int out_size, void* d_ws, size_t ws_size,
                              hipStream_t stream) {
    (void)in_sizes; (void)n_in; (void)out_size; (void)ws_size;
    const float* x  = (const float*)d_in[0];
    const float* Wx = (const float*)d_in[1];
    const float* Wy = (const float*)d_in[2];
    const float* by = (const float*)d_in[3];
    float* out = (float*)d_out;

    char* ws = (char*)d_ws;
    const size_t MB = 1024ull * 1024ull;
    f16* st16a = (f16*)(ws);             // 32 MiB: x_f16 during proj, then state ping
    f16* st16b = (f16*)(ws + 32 * MB);   // 32 MiB: state pong
    f16* P16   = (f16*)(ws + 64 * MB);   // 32 MiB: projection, fp16
    f16* WxT   = (f16*)(ws + 96 * MB);   // 2 MiB
    f16* WyT   = (f16*)(ws + 98 * MB);   // 4 MiB

    hipLaunchKernelGGL(k_f32_to_f16, dim3(MROWS * H / 8 / 256), dim3(256), 0, stream, x, st16a);
    hipLaunchKernelGGL(k_transpose_f16, dim3(H / 32, H / 32), dim3(32, 8), 0, stream, Wx, WxT, H, H);
    hipLaunchKernelGGL(k_transpose_f16, dim3(2 * H / 32, H / 32), dim3(32, 8), 0, stream, Wy, WyT, H, 2 * H);
    hipLaunchKernelGGL(k_proj_gemm, dim3(MROWS / 128, H / 128), dim3(256), 0, stream, st16a, WxT, P16);
    hipLaunchKernelGGL(k_step0, dim3(MROWS * H / 8 / 256), dim3(256), 0, stream, P16, by, st16b);

    f16* bufs[2] = {st16a, st16b};
    for (int i = 1; i <= 15; ++i) {
        const f16* cur = bufs[i & 1];
        f16* nxt = bufs[(i + 1) & 1];
        hipLaunchKernelGGL(k_step_gemm256, dim3(MROWS / 256 * 8), dim3(512), 0, stream,
                           cur, WyT, P16, by, out, nxt, i);
    }
}